// Round 12
// baseline (2189.625 us; speedup 1.0000x reference)
//
#include <hip/hip_runtime.h>
#include <hip/hip_bf16.h>
#include <hip/hip_fp16.h>

#define NDIM_IN 128
#define HID 64

#define BINW 128          // dst values per bin
#define NB   782          // ceil(100000/128)
#define NC   256          // phase-1 blocks == scan1 block size (alignment!)

typedef _Float16 f16x8 __attribute__((ext_vector_type(8)));
typedef float f32x4 __attribute__((ext_vector_type(4)));

// ---------------------------------------------------------------------------
// Phase 1a: per-block LDS histogram over bins, written transposed.
// ---------------------------------------------------------------------------
__global__ __launch_bounds__(256) void hist_k(const int* __restrict__ dst,
                                              int* __restrict__ histT, int E) {
  __shared__ int h[NB];
  for (int i = threadIdx.x; i < NB; i += 256) h[i] = 0;
  __syncthreads();
  int E4 = E >> 2;
  int chunk = (E4 + NC - 1) / NC;
  int beg = blockIdx.x * chunk;
  int end = min(E4, beg + chunk);
  const int4* __restrict__ d4 = (const int4*)dst;
  for (int i = beg + (int)threadIdx.x; i < end; i += 256) {
    int4 d = d4[i];
    atomicAdd(&h[d.x >> 7], 1);
    atomicAdd(&h[d.y >> 7], 1);
    atomicAdd(&h[d.z >> 7], 1);
    atomicAdd(&h[d.w >> 7], 1);
  }
  __syncthreads();
  for (int i = threadIdx.x; i < NB; i += 256)
    histT[i * NC + blockIdx.x] = h[i];
}

// ---------------------------------------------------------------------------
// scan1/scan2: block size == NC so bsum[bin] becomes the global bin base.
// ---------------------------------------------------------------------------
__global__ __launch_bounds__(256) void scan1(int* __restrict__ g,
                                             int* __restrict__ bs, int len) {
  __shared__ int s[256];
  int t = threadIdx.x;
  int i = blockIdx.x * 256 + t;
  int v = (i < len) ? g[i] : 0;
  s[t] = v;
  __syncthreads();
  for (int off = 1; off < 256; off <<= 1) {
    int x = (t >= off) ? s[t - off] : 0;
    __syncthreads();
    s[t] += x;
    __syncthreads();
  }
  if (i < len) g[i] = s[t] - v;
  if (t == 255) bs[blockIdx.x] = s[255];
}

__global__ __launch_bounds__(1024) void scan2(int* __restrict__ bs, int nb) {
  __shared__ int s[1024];
  int t = threadIdx.x;
  int v = (t < nb) ? bs[t] : 0;
  s[t] = v;
  __syncthreads();
  for (int off = 1; off < 1024; off <<= 1) {
    int x = (t >= off) ? s[t - off] : 0;
    __syncthreads();
    s[t] += x;
    __syncthreads();
  }
  if (t < nb) bs[t] = s[t] - v;
}

// ---------------------------------------------------------------------------
// Phase 1c: scatter packed (src<<7 | dst&127) into tmp, grouped by bin.
// ---------------------------------------------------------------------------
__global__ __launch_bounds__(256) void scatter_k(const int* __restrict__ src,
                                                 const int* __restrict__ dst,
                                                 const int* __restrict__ S,
                                                 const int* __restrict__ bsum,
                                                 int* __restrict__ tmp, int E) {
  __shared__ int cur[NB];
  for (int i = threadIdx.x; i < NB; i += 256)
    cur[i] = S[i * NC + blockIdx.x] + bsum[i];
  __syncthreads();
  int E4 = E >> 2;
  int chunk = (E4 + NC - 1) / NC;
  int beg = blockIdx.x * chunk;
  int end = min(E4, beg + chunk);
  const int4* __restrict__ d4 = (const int4*)dst;
  const int4* __restrict__ s4 = (const int4*)src;
  for (int i = beg + (int)threadIdx.x; i < end; i += 256) {
    int4 d = d4[i];
    int4 sv = s4[i];
    int p0 = atomicAdd(&cur[d.x >> 7], 1); tmp[p0] = (sv.x << 7) | (d.x & 127);
    int p1 = atomicAdd(&cur[d.y >> 7], 1); tmp[p1] = (sv.y << 7) | (d.y & 127);
    int p2 = atomicAdd(&cur[d.z >> 7], 1); tmp[p2] = (sv.z << 7) | (d.z & 127);
    int p3 = atomicAdd(&cur[d.w >> 7], 1); tmp[p3] = (sv.w << 7) | (d.w & 127);
  }
}

// ---------------------------------------------------------------------------
// dinv from per-dst counts within each bin (replaces binsort entirely).
// ---------------------------------------------------------------------------
__global__ __launch_bounds__(256) void dinv_k(const int* __restrict__ tmp,
                                              const int* __restrict__ bsum,
                                              float* __restrict__ dinv,
                                              int n, int E) {
  __shared__ int cnt[BINW];
  int bin = blockIdx.x;
  int t = threadIdx.x;
  if (t < BINW) cnt[t] = 0;
  __syncthreads();
  int base = bsum[bin];
  int endv = (bin == NB - 1) ? E : bsum[bin + 1];
  for (int i = base + t; i < endv; i += 256)
    atomicAdd(&cnt[tmp[i] & (BINW - 1)], 1);
  __syncthreads();
  if (t < BINW) {
    int v = bin * BINW + t;
    if (v < n) dinv[v] = rsqrtf((float)cnt[t] + 1.0f);  // +1 = self loop
  }
}

// ---------------------------------------------------------------------------
// MFMA dense transform (layer 1 only): T' = (X @ W) * dinv[row], fp16 out.
// (R11 verified kernel, unchanged.)
// ---------------------------------------------------------------------------
template <int K>
__global__ __launch_bounds__(256) void gemm_mfma(const float* __restrict__ X,
                                                 const float* __restrict__ W,
                                                 const float* __restrict__ dinv,
                                                 __half* __restrict__ T,
                                                 int n, int ntiles) {
  constexpr int NCH = K / 32;
  __shared__ float Ds[4][16 * 68];
  int wv = threadIdx.x >> 6;
  int lane = threadIdx.x & 63;
  int colx = lane & 15;
  int quad = lane >> 4;

  f16x8 bf[4][NCH];
#pragma unroll
  for (int t = 0; t < 4; t++)
#pragma unroll
    for (int c = 0; c < NCH; c++) {
      f16x8 b;
#pragma unroll
      for (int j = 0; j < 8; j++)
        b[j] = (_Float16)W[(32 * c + quad * 8 + j) * 64 + 16 * t + colx];
      bf[t][c] = b;
    }

  for (int tile = blockIdx.x * 4 + wv; tile < ntiles; tile += gridDim.x * 4) {
    int node0 = tile * 16;
    f32x4 acc[4] = {{0.f, 0.f, 0.f, 0.f}, {0.f, 0.f, 0.f, 0.f},
                    {0.f, 0.f, 0.f, 0.f}, {0.f, 0.f, 0.f, 0.f}};
    int arow = min(node0 + colx, n - 1);
    const float* __restrict__ xr = X + (size_t)arow * K;
#pragma unroll
    for (int c = 0; c < NCH; c++) {
      float4 x0 = *(const float4*)(xr + 32 * c + quad * 8);
      float4 x1 = *(const float4*)(xr + 32 * c + quad * 8 + 4);
      f16x8 a;
      a[0] = (_Float16)x0.x; a[1] = (_Float16)x0.y;
      a[2] = (_Float16)x0.z; a[3] = (_Float16)x0.w;
      a[4] = (_Float16)x1.x; a[5] = (_Float16)x1.y;
      a[6] = (_Float16)x1.z; a[7] = (_Float16)x1.w;
#pragma unroll
      for (int t = 0; t < 4; t++)
        acc[t] = __builtin_amdgcn_mfma_f32_16x16x32_f16(a, bf[t][c], acc[t], 0, 0, 0);
    }
    float dv[4];
#pragma unroll
    for (int r = 0; r < 4; r++) {
      int nd = min(node0 + quad * 4 + r, n - 1);
      dv[r] = dinv[nd];
    }
#pragma unroll
    for (int t = 0; t < 4; t++)
#pragma unroll
      for (int r = 0; r < 4; r++)
        Ds[wv][(quad * 4 + r) * 68 + 16 * t + colx] = acc[t][r] * dv[r];
    int nd = node0 + colx;
    const float* __restrict__ row = &Ds[wv][colx * 68 + quad * 16];
    float4 y0 = *(const float4*)(row + 0);
    float4 y1 = *(const float4*)(row + 4);
    float4 y2 = *(const float4*)(row + 8);
    float4 y3 = *(const float4*)(row + 12);
    f16x8 o0, o1;
    o0[0] = (_Float16)y0.x; o0[1] = (_Float16)y0.y;
    o0[2] = (_Float16)y0.z; o0[3] = (_Float16)y0.w;
    o0[4] = (_Float16)y1.x; o0[5] = (_Float16)y1.y;
    o0[6] = (_Float16)y1.z; o0[7] = (_Float16)y1.w;
    o1[0] = (_Float16)y2.x; o1[1] = (_Float16)y2.y;
    o1[2] = (_Float16)y2.z; o1[3] = (_Float16)y2.w;
    o1[4] = (_Float16)y3.x; o1[5] = (_Float16)y3.y;
    o1[6] = (_Float16)y3.z; o1[7] = (_Float16)y3.w;
    if (nd < n) {
      uint4* __restrict__ o = (uint4*)(T + (size_t)nd * 64 + quad * 16);
      o[0] = *(uint4*)&o0;
      o[1] = *(uint4*)&o1;
    }
  }
}

// ---------------------------------------------------------------------------
// Fused layer: block per bin (128 dst nodes). Init LDS H with self-loop rows
// from Tin; gather T'[src] per edge straight from tmp (8-row group gathers,
// 4 chains = 32 edges in flight) + ds_add_f32 accumulate; then
//   MODE 0: H=relu(dinv*agg+bias); Tout=(H@Wn)*dinv via MFMA (fp16)
//   MODE 1: write H=relu(dinv*agg+bias) as f32 to Hout (for mlp_head)
// Kills binsort/col/rp + standalone gemm for layers 2,3.
// ---------------------------------------------------------------------------
template <int MODE>
__global__ __launch_bounds__(256) void fused_layer(
    const int* __restrict__ tmp, const int* __restrict__ bsum,
    const __half* __restrict__ Tin, const float* __restrict__ dinv,
    const float* __restrict__ bias, const float* __restrict__ Wn,
    __half* __restrict__ Tout, float* __restrict__ Hout, int n, int E) {
  __shared__ float Hs[128 * 65];   // 33.3 KB; rows stride 65 (conflict-free)
  int bin = blockIdx.x;
  int t = threadIdx.x;
  int wv = t >> 6, lane = t & 63;
  int colx = lane & 15, quad = lane >> 4;
  int node00 = bin * BINW;

  f16x8 bf[4][2];
  if (MODE == 0) {
#pragma unroll
    for (int nt = 0; nt < 4; nt++)
#pragma unroll
      for (int c = 0; c < 2; c++) {
        f16x8 b;
#pragma unroll
        for (int j = 0; j < 8; j++)
          b[j] = (_Float16)Wn[(32 * c + quad * 8 + j) * 64 + 16 * nt + colx];
        bf[nt][c] = b;
      }
  }

  // init Hs = T'[v] (self loop); pad rows -> 0
  const uint4* __restrict__ Tin8 = (const uint4*)Tin;
#pragma unroll
  for (int i = 0; i < 4; i++) {
    int idx = t + 256 * i;           // 0..1023 = 128 rows x 8 uint4
    int row = idx >> 3, su = idx & 7;
    int v = node00 + row;
    float f[8] = {0.f, 0.f, 0.f, 0.f, 0.f, 0.f, 0.f, 0.f};
    if (v < n) {
      uint4 w = Tin8[(size_t)v * 8 + su];
      const __half2* h = (const __half2*)&w;
#pragma unroll
      for (int j = 0; j < 4; j++) {
        float2 ff = __half22float2(h[j]);
        f[2 * j] = ff.x; f[2 * j + 1] = ff.y;
      }
    }
    float* p = &Hs[row * 65 + su * 8];
#pragma unroll
    for (int j = 0; j < 8; j++) p[j] = f[j];
  }
  __syncthreads();

  // edge accumulation
  int base = bsum[bin];
  int endv = (bin == NB - 1) ? E : bsum[bin + 1];
  int g = lane >> 3, su8 = lane & 7;
  for (int e0 = base + wv * 32; e0 < endv; e0 += 128) {
#pragma unroll
    for (int c = 0; c < 4; c++) {
      int i = e0 + 8 * c + g;
      if (i < endv) {
        int p = tmp[i];
        int s = p >> 7, d = p & (BINW - 1);
        uint4 w = Tin8[(size_t)s * 8 + su8];
        const __half2* h = (const __half2*)&w;
        float* hp = &Hs[d * 65 + su8 * 8];
#pragma unroll
        for (int j = 0; j < 4; j++) {
          float2 ff = __half22float2(h[j]);
          atomicAdd(&hp[2 * j], ff.x);
          atomicAdd(&hp[2 * j + 1], ff.y);
        }
      }
    }
  }
  __syncthreads();

  if (MODE == 0) {
    // bias regs: k = 32c + quad*8 + j
    float brg[2][8];
#pragma unroll
    for (int c = 0; c < 2; c++) {
      float4 bA = *(const float4*)(bias + 32 * c + quad * 8);
      float4 bB = *(const float4*)(bias + 32 * c + quad * 8 + 4);
      brg[c][0] = bA.x; brg[c][1] = bA.y; brg[c][2] = bA.z; brg[c][3] = bA.w;
      brg[c][4] = bB.x; brg[c][5] = bB.y; brg[c][6] = bB.z; brg[c][7] = bB.w;
    }
    f16x8 af[2][2];
    float dvo[2][4];
#pragma unroll
    for (int t2 = 0; t2 < 2; t2++) {
      int row0 = wv * 32 + t2 * 16;
      int nodeA = node00 + row0 + colx;
      float dA = (nodeA < n) ? dinv[nodeA] : 0.f;
#pragma unroll
      for (int c = 0; c < 2; c++) {
        const float* hr = &Hs[(row0 + colx) * 65 + 32 * c + quad * 8];
        f16x8 a;
#pragma unroll
        for (int j = 0; j < 8; j++) {
          float h = dA * hr[j] + brg[c][j];
          a[j] = (_Float16)(h > 0.f ? h : 0.f);
        }
        af[t2][c] = a;
      }
#pragma unroll
      for (int r = 0; r < 4; r++) {
        int nd = node00 + row0 + quad * 4 + r;
        dvo[t2][r] = (nd < n) ? dinv[nd] : 0.f;
      }
    }
    __syncthreads();            // all A-frags read; Ds may alias Hs
    float* Ds = &Hs[wv * 1088]; // 16*68 floats per wave
#pragma unroll
    for (int t2 = 0; t2 < 2; t2++) {
      f32x4 acc[4] = {{0.f, 0.f, 0.f, 0.f}, {0.f, 0.f, 0.f, 0.f},
                      {0.f, 0.f, 0.f, 0.f}, {0.f, 0.f, 0.f, 0.f}};
#pragma unroll
      for (int c = 0; c < 2; c++)
#pragma unroll
        for (int nt = 0; nt < 4; nt++)
          acc[nt] = __builtin_amdgcn_mfma_f32_16x16x32_f16(af[t2][c], bf[nt][c],
                                                           acc[nt], 0, 0, 0);
#pragma unroll
      for (int nt = 0; nt < 4; nt++)
#pragma unroll
        for (int r = 0; r < 4; r++)
          Ds[(quad * 4 + r) * 68 + 16 * nt + colx] = acc[nt][r] * dvo[t2][r];
      int row0 = wv * 32 + t2 * 16;
      int nd = node00 + row0 + colx;
      const float* rrow = &Ds[colx * 68 + quad * 16];
      float4 y0 = *(const float4*)(rrow + 0);
      float4 y1 = *(const float4*)(rrow + 4);
      float4 y2 = *(const float4*)(rrow + 8);
      float4 y3 = *(const float4*)(rrow + 12);
      f16x8 o0, o1;
      o0[0] = (_Float16)y0.x; o0[1] = (_Float16)y0.y;
      o0[2] = (_Float16)y0.z; o0[3] = (_Float16)y0.w;
      o0[4] = (_Float16)y1.x; o0[5] = (_Float16)y1.y;
      o0[6] = (_Float16)y1.z; o0[7] = (_Float16)y1.w;
      o1[0] = (_Float16)y2.x; o1[1] = (_Float16)y2.y;
      o1[2] = (_Float16)y2.z; o1[3] = (_Float16)y2.w;
      o1[4] = (_Float16)y3.x; o1[5] = (_Float16)y3.y;
      o1[6] = (_Float16)y3.z; o1[7] = (_Float16)y3.w;
      if (nd < n) {
        uint4* __restrict__ o = (uint4*)(Tout + (size_t)nd * 64 + quad * 16);
        o[0] = *(uint4*)&o0;
        o[1] = *(uint4*)&o1;
      }
    }
  } else {
    // MODE 1: H f32 out for mlp_head
#pragma unroll
    for (int i = 0; i < 8; i++) {
      int idx = t + 256 * i;          // 0..2047 = 128 rows x 16 float4
      int row = idx >> 4, c4 = idx & 15;
      int v = node00 + row;
      if (v < n) {
        float dv = dinv[v];
        float4 b4 = *(const float4*)(bias + c4 * 4);
        const float* hr = &Hs[row * 65 + c4 * 4];
        float4 r;
        r.x = dv * hr[0] + b4.x; r.y = dv * hr[1] + b4.y;
        r.z = dv * hr[2] + b4.z; r.w = dv * hr[3] + b4.w;
        r.x = r.x > 0.f ? r.x : 0.f;
        r.y = r.y > 0.f ? r.y : 0.f;
        r.z = r.z > 0.f ? r.z : 0.f;
        r.w = r.w > 0.f ? r.w : 0.f;
        *(float4*)(Hout + (size_t)v * 64 + c4 * 4) = r;
      }
    }
  }
}

// ---------------------------------------------------------------------------
// Fused MLP head: out = relu(H @ Wp1 + bp1) @ Wp2 + bp2, thread-per-node
// ---------------------------------------------------------------------------
__global__ __launch_bounds__(256) void mlp_head(const float* __restrict__ H,
                                                const float* __restrict__ Wp1,
                                                const float* __restrict__ bp1,
                                                const float* __restrict__ Wp2,
                                                const float* __restrict__ bp2,
                                                float* __restrict__ out, int n) {
  __shared__ float W1t[32 * 64];
  __shared__ float w2s[32];
  __shared__ float b1s[32];
  for (int i = threadIdx.x; i < 64 * 32; i += 256) {
    int k = i >> 5, j = i & 31;
    W1t[j * 64 + k] = Wp1[i];
  }
  if (threadIdx.x < 32) {
    w2s[threadIdx.x] = Wp2[threadIdx.x];
    b1s[threadIdx.x] = bp1[threadIdx.x];
  }
  __syncthreads();
  int node = blockIdx.x * 256 + threadIdx.x;
  if (node >= n) return;
  float4 h[16];
  const float4* __restrict__ hr = (const float4*)(H + (size_t)node * 64);
#pragma unroll
  for (int j = 0; j < 16; j++) h[j] = hr[j];
  float o = bp2[0];
#pragma unroll
  for (int j = 0; j < 32; j++) {
    const float4* wr = (const float4*)(W1t + j * 64);
    float4 a4 = make_float4(0.f, 0.f, 0.f, 0.f);
#pragma unroll
    for (int k = 0; k < 16; k++) {
      float4 w = wr[k];
      a4.x += h[k].x * w.x;
      a4.y += h[k].y * w.y;
      a4.z += h[k].z * w.z;
      a4.w += h[k].w * w.w;
    }
    float a = a4.x + a4.y + a4.z + a4.w + b1s[j];
    a = a > 0.f ? a : 0.f;
    o += a * w2s[j];
  }
  out[node] = o;
}

// ---------------------------------------------------------------------------
extern "C" void kernel_launch(void* const* d_in, const int* in_sizes, int n_in,
                              void* d_out, int out_size, void* d_ws, size_t ws_size,
                              hipStream_t stream) {
  const float* x   = (const float*)d_in[0];
  const int* edge  = (const int*)d_in[1];
  const float* W1  = (const float*)d_in[3];
  const float* b1  = (const float*)d_in[4];
  const float* W2  = (const float*)d_in[5];
  const float* b2  = (const float*)d_in[6];
  const float* W3  = (const float*)d_in[7];
  const float* b3  = (const float*)d_in[8];
  const float* Wp1 = (const float*)d_in[9];
  const float* bp1 = (const float*)d_in[10];
  const float* Wp2 = (const float*)d_in[11];
  const float* bp2 = (const float*)d_in[12];
  float* out = (float*)d_out;

  const int n = in_sizes[0] / NDIM_IN;   // 100000
  const int E = in_sizes[1] / 2;         // 1600000
  const int* src = edge;
  const int* dst = edge + E;

  // workspace carve-out (256B aligned slices)
  char* ws = (char*)d_ws;
  size_t off = 0;
  auto carve = [&](size_t bytes) {
    char* p = ws + off;
    off = (off + bytes + 255) & ~(size_t)255;
    return p;
  };
  int*    histT = (int*)carve((size_t)NB * NC * 4);   // 800 KB
  int*    bsum  = (int*)carve(1024 * 4);
  int*    tmp   = (int*)carve((size_t)E * 4);         // 6.4 MB (packed)
  float*  dinv  = (float*)carve((size_t)n * 4);
  __half* bufT  = (__half*)carve((size_t)n * HID * 2);   // 12.8 MB
  __half* bufT2 = (__half*)carve((size_t)n * HID * 2);   // 12.8 MB (ping-pong)
  float*  bufA  = (float*)carve((size_t)n * HID * 4);    // 25.6 MB (H3)
  (void)ws_size; (void)n_in; (void)out_size;

  const int nbN = (n + 255) / 256;        // 391
  const int ntiles = (n + 15) >> 4;       // 6250
  const int scan_len = NB * NC;           // 200192
  const int nbScan = (scan_len + 255) / 256;  // 782 == NB (alignment!)

  hist_k<<<NC, 256, 0, stream>>>(dst, histT, E);
  scan1<<<nbScan, 256, 0, stream>>>(histT, bsum, scan_len);
  scan2<<<1, 1024, 0, stream>>>(bsum, nbScan);
  scatter_k<<<NC, 256, 0, stream>>>(src, dst, histT, bsum, tmp, E);
  dinv_k<<<NB, 256, 0, stream>>>(tmp, bsum, dinv, n, E);

  // layer 1 transform: T1 = (X@W1)*dinv
  gemm_mfma<128><<<782, 256, 0, stream>>>(x, W1, dinv, bufT, n, ntiles);
  // fused layer 1->2: H1=relu(dinv*agg(T1)+b1); T2=(H1@W2)*dinv
  fused_layer<0><<<NB, 256, 0, stream>>>(tmp, bsum, bufT, dinv, b1, W2,
                                         bufT2, nullptr, n, E);
  // fused layer 2->3: T3=(H2@W3)*dinv
  fused_layer<0><<<NB, 256, 0, stream>>>(tmp, bsum, bufT2, dinv, b2, W3,
                                         bufT, nullptr, n, E);
  // fused layer 3: H3 (f32)
  fused_layer<1><<<NB, 256, 0, stream>>>(tmp, bsum, bufT, dinv, b3, nullptr,
                                         nullptr, bufA, n, E);
  // head
  mlp_head<<<nbN, 256, 0, stream>>>(bufA, Wp1, bp1, Wp2, bp2, out, n);
}

// Round 13
// 548.843 us; speedup vs baseline: 3.9895x; 3.9895x over previous
//
#include <hip/hip_runtime.h>
#include <hip/hip_bf16.h>
#include <hip/hip_fp16.h>

#define NDIM_IN 128
#define HID 64

#define BINW 128          // dst values per bin
#define NB   782          // ceil(100000/128)
#define NC   256          // phase-1 blocks == scan1 block size (alignment!)
#define CAP  3072         // LDS edge buffer per bin (mean 2046, +22 sigma)

typedef _Float16 f16x8 __attribute__((ext_vector_type(8)));
typedef float f32x4 __attribute__((ext_vector_type(4)));

// ---------------------------------------------------------------------------
// Phase 1a: per-block LDS histogram over bins, written transposed.
// ---------------------------------------------------------------------------
__global__ __launch_bounds__(256) void hist_k(const int* __restrict__ dst,
                                              int* __restrict__ histT, int E) {
  __shared__ int h[NB];
  for (int i = threadIdx.x; i < NB; i += 256) h[i] = 0;
  __syncthreads();
  int E4 = E >> 2;
  int chunk = (E4 + NC - 1) / NC;
  int beg = blockIdx.x * chunk;
  int end = min(E4, beg + chunk);
  const int4* __restrict__ d4 = (const int4*)dst;
  for (int i = beg + (int)threadIdx.x; i < end; i += 256) {
    int4 d = d4[i];
    atomicAdd(&h[d.x >> 7], 1);
    atomicAdd(&h[d.y >> 7], 1);
    atomicAdd(&h[d.z >> 7], 1);
    atomicAdd(&h[d.w >> 7], 1);
  }
  __syncthreads();
  for (int i = threadIdx.x; i < NB; i += 256)
    histT[i * NC + blockIdx.x] = h[i];
}

// ---------------------------------------------------------------------------
// scan1/scan2: block size == NC so bsum[bin] becomes the global bin base.
// ---------------------------------------------------------------------------
__global__ __launch_bounds__(256) void scan1(int* __restrict__ g,
                                             int* __restrict__ bs, int len) {
  __shared__ int s[256];
  int t = threadIdx.x;
  int i = blockIdx.x * 256 + t;
  int v = (i < len) ? g[i] : 0;
  s[t] = v;
  __syncthreads();
  for (int off = 1; off < 256; off <<= 1) {
    int x = (t >= off) ? s[t - off] : 0;
    __syncthreads();
    s[t] += x;
    __syncthreads();
  }
  if (i < len) g[i] = s[t] - v;
  if (t == 255) bs[blockIdx.x] = s[255];
}

__global__ __launch_bounds__(1024) void scan2(int* __restrict__ bs, int nb) {
  __shared__ int s[1024];
  int t = threadIdx.x;
  int v = (t < nb) ? bs[t] : 0;
  s[t] = v;
  __syncthreads();
  for (int off = 1; off < 1024; off <<= 1) {
    int x = (t >= off) ? s[t - off] : 0;
    __syncthreads();
    s[t] += x;
    __syncthreads();
  }
  if (t < nb) bs[t] = s[t] - v;
}

// ---------------------------------------------------------------------------
// Phase 1c: scatter packed (src<<7 | dst&127) into tmp, grouped by bin.
// ---------------------------------------------------------------------------
__global__ __launch_bounds__(256) void scatter_k(const int* __restrict__ src,
                                                 const int* __restrict__ dst,
                                                 const int* __restrict__ S,
                                                 const int* __restrict__ bsum,
                                                 int* __restrict__ tmp, int E) {
  __shared__ int cur[NB];
  for (int i = threadIdx.x; i < NB; i += 256)
    cur[i] = S[i * NC + blockIdx.x] + bsum[i];
  __syncthreads();
  int E4 = E >> 2;
  int chunk = (E4 + NC - 1) / NC;
  int beg = blockIdx.x * chunk;
  int end = min(E4, beg + chunk);
  const int4* __restrict__ d4 = (const int4*)dst;
  const int4* __restrict__ s4 = (const int4*)src;
  for (int i = beg + (int)threadIdx.x; i < end; i += 256) {
    int4 d = d4[i];
    int4 sv = s4[i];
    int p0 = atomicAdd(&cur[d.x >> 7], 1); tmp[p0] = (sv.x << 7) | (d.x & 127);
    int p1 = atomicAdd(&cur[d.y >> 7], 1); tmp[p1] = (sv.y << 7) | (d.y & 127);
    int p2 = atomicAdd(&cur[d.z >> 7], 1); tmp[p2] = (sv.z << 7) | (d.z & 127);
    int p3 = atomicAdd(&cur[d.w >> 7], 1); tmp[p3] = (sv.w << 7) | (d.w & 127);
  }
}

// ---------------------------------------------------------------------------
// Phase 2: one block per bin; in-LDS counting sort -> col, rp, dinv.
// ---------------------------------------------------------------------------
__global__ __launch_bounds__(256) void binsort_k(const int* __restrict__ tmp,
                                                 const int* __restrict__ bsum,
                                                 int* __restrict__ col,
                                                 int* __restrict__ rp,
                                                 float* __restrict__ dinv,
                                                 int n, int E) {
  int bin = blockIdx.x;
  int base = bsum[bin];
  int end = (bin == NB - 1) ? E : bsum[bin + 1];
  int m = end - base;
  __shared__ int cnt[BINW];
  __shared__ int offs[BINW];
  __shared__ int cur[BINW];
  __shared__ int buf[CAP];
  int t = threadIdx.x;
  if (t < BINW) cnt[t] = 0;
  __syncthreads();
  for (int i = t; i < m; i += 256) {
    int p = tmp[base + i];
    atomicAdd(&cnt[p & (BINW - 1)], 1);
  }
  __syncthreads();
  if (t < BINW) offs[t] = cnt[t];
  __syncthreads();
  for (int off = 1; off < BINW; off <<= 1) {
    int x = (t < BINW && t >= off) ? offs[t - off] : 0;
    __syncthreads();
    if (t < BINW) offs[t] += x;
    __syncthreads();
  }
  if (t < BINW) {
    int ex = offs[t] - cnt[t];
    cur[t] = ex;
    int v = bin * BINW + t;
    if (v < n) {
      rp[v] = base + ex;
      dinv[v] = rsqrtf((float)cnt[t] + 1.0f);  // +1 = self loop
    }
  }
  if (bin == NB - 1 && t == 0) rp[n] = E;
  __syncthreads();
  for (int i = t; i < m; i += 256) {
    int p = tmp[base + i];
    int r = atomicAdd(&cur[p & (BINW - 1)], 1);
    if (r < CAP) buf[r] = p >> 7;
  }
  __syncthreads();
  int mm = min(m, CAP);
  for (int i = t; i < mm; i += 256) col[base + i] = buf[i];
}

// ---------------------------------------------------------------------------
// MFMA dense transform: T' = (X @ W) * dinv[row], output fp16 in FEATURE-
// SLICED layout: slice s (16 feats) at T + s*n*16. Slice index == quad, so
// only the epilogue store address changes vs the verified R11 kernel.
// ---------------------------------------------------------------------------
template <int K>
__global__ __launch_bounds__(256) void gemm_mfma(const float* __restrict__ X,
                                                 const float* __restrict__ W,
                                                 const float* __restrict__ dinv,
                                                 __half* __restrict__ T,
                                                 int n, int ntiles) {
  constexpr int NCH = K / 32;
  __shared__ float Ds[4][16 * 68];
  int wv = threadIdx.x >> 6;
  int lane = threadIdx.x & 63;
  int colx = lane & 15;
  int quad = lane >> 4;

  f16x8 bf[4][NCH];
#pragma unroll
  for (int t = 0; t < 4; t++)
#pragma unroll
    for (int c = 0; c < NCH; c++) {
      f16x8 b;
#pragma unroll
      for (int j = 0; j < 8; j++)
        b[j] = (_Float16)W[(32 * c + quad * 8 + j) * 64 + 16 * t + colx];
      bf[t][c] = b;
    }

  for (int tile = blockIdx.x * 4 + wv; tile < ntiles; tile += gridDim.x * 4) {
    int node0 = tile * 16;
    f32x4 acc[4] = {{0.f, 0.f, 0.f, 0.f}, {0.f, 0.f, 0.f, 0.f},
                    {0.f, 0.f, 0.f, 0.f}, {0.f, 0.f, 0.f, 0.f}};
    int arow = min(node0 + colx, n - 1);
    const float* __restrict__ xr = X + (size_t)arow * K;
#pragma unroll
    for (int c = 0; c < NCH; c++) {
      float4 x0 = *(const float4*)(xr + 32 * c + quad * 8);
      float4 x1 = *(const float4*)(xr + 32 * c + quad * 8 + 4);
      f16x8 a;
      a[0] = (_Float16)x0.x; a[1] = (_Float16)x0.y;
      a[2] = (_Float16)x0.z; a[3] = (_Float16)x0.w;
      a[4] = (_Float16)x1.x; a[5] = (_Float16)x1.y;
      a[6] = (_Float16)x1.z; a[7] = (_Float16)x1.w;
#pragma unroll
      for (int t = 0; t < 4; t++)
        acc[t] = __builtin_amdgcn_mfma_f32_16x16x32_f16(a, bf[t][c], acc[t], 0, 0, 0);
    }
    float dv[4];
#pragma unroll
    for (int r = 0; r < 4; r++) {
      int nd = min(node0 + quad * 4 + r, n - 1);
      dv[r] = dinv[nd];
    }
#pragma unroll
    for (int t = 0; t < 4; t++)
#pragma unroll
      for (int r = 0; r < 4; r++)
        Ds[wv][(quad * 4 + r) * 68 + 16 * t + colx] = acc[t][r] * dv[r];
    int nd = node0 + colx;
    const float* __restrict__ row = &Ds[wv][colx * 68 + quad * 16];
    float4 y0 = *(const float4*)(row + 0);
    float4 y1 = *(const float4*)(row + 4);
    float4 y2 = *(const float4*)(row + 8);
    float4 y3 = *(const float4*)(row + 12);
    f16x8 o0, o1;
    o0[0] = (_Float16)y0.x; o0[1] = (_Float16)y0.y;
    o0[2] = (_Float16)y0.z; o0[3] = (_Float16)y0.w;
    o0[4] = (_Float16)y1.x; o0[5] = (_Float16)y1.y;
    o0[6] = (_Float16)y1.z; o0[7] = (_Float16)y1.w;
    o1[0] = (_Float16)y2.x; o1[1] = (_Float16)y2.y;
    o1[2] = (_Float16)y2.z; o1[3] = (_Float16)y2.w;
    o1[4] = (_Float16)y3.x; o1[5] = (_Float16)y3.y;
    o1[6] = (_Float16)y3.z; o1[7] = (_Float16)y3.w;
    if (nd < n) {
      // sliced store: slice=quad, row nd, 16 halves = 2 uint4
      uint4* __restrict__ o = (uint4*)(T + ((size_t)quad * n + nd) * 16);
      o[0] = *(uint4*)&o0;
      o[1] = *(uint4*)&o1;
    }
  }
}

// ---------------------------------------------------------------------------
// SpMM gather, XCD-local slices: block b -> slice b&3, node chunk b>>2
// (4 nodes, wave-per-node). blockIdx%8 round-robins XCDs => XCD x only
// touches slice x%4 (3.2 MB, L2-resident). 16 groups x 4 lanes x uint2:
// ONE gather instruction covers 16 edges; 2 rounds cover deg<32.
// ---------------------------------------------------------------------------
__global__ __launch_bounds__(256) void spmm_relu(const int* __restrict__ rp,
                                                 const int* __restrict__ col,
                                                 const __half* __restrict__ T,
                                                 const float* __restrict__ dinv,
                                                 const float* __restrict__ bias,
                                                 float* __restrict__ H, int n) {
  int b = blockIdx.x;
  int slice = b & 3;
  int v = (b >> 2) * 4 + (threadIdx.x >> 6);
  int lane = threadIdx.x & 63;
  if (v >= n) return;
  int g = lane >> 2;           // edge group 0..15
  int sub = lane & 3;          // uint2 index (feats 4*sub..+3 of slice)
  const uint2* __restrict__ Ts = (const uint2*)(T + (size_t)slice * n * 16);
  int beg = rp[v], end = rp[v + 1];

  float a0[4] = {0.f, 0.f, 0.f, 0.f};
  float a1[4] = {0.f, 0.f, 0.f, 0.f};
  if (g == 0) {  // self loop: group 0 adds T'[v] exactly once
    uint2 w = Ts[(size_t)v * 4 + sub];
    const __half2* h = (const __half2*)&w;
    float2 f0 = __half22float2(h[0]);
    float2 f1 = __half22float2(h[1]);
    a0[0] += f0.x; a0[1] += f0.y; a0[2] += f1.x; a0[3] += f1.y;
  }
  int efull = beg + ((end - beg) & ~31);
  for (int e = beg; e < efull; e += 32) {
    int s0 = col[e + g];
    int s1 = col[e + 16 + g];
    uint2 w0 = Ts[(size_t)s0 * 4 + sub];
    uint2 w1 = Ts[(size_t)s1 * 4 + sub];
    const __half2* h0 = (const __half2*)&w0;
    const __half2* h1 = (const __half2*)&w1;
    float2 f00 = __half22float2(h0[0]), f01 = __half22float2(h0[1]);
    float2 f10 = __half22float2(h1[0]), f11 = __half22float2(h1[1]);
    a0[0] += f00.x; a0[1] += f00.y; a0[2] += f01.x; a0[3] += f01.y;
    a1[0] += f10.x; a1[1] += f10.y; a1[2] += f11.x; a1[3] += f11.y;
  }
  {  // tail (<32 edges): 2 exec-guarded rounds of 16
    int i0 = efull + g, i1 = efull + 16 + g;
    if (i0 < end) {
      uint2 w = Ts[(size_t)col[i0] * 4 + sub];
      const __half2* h = (const __half2*)&w;
      float2 f0 = __half22float2(h[0]), f1 = __half22float2(h[1]);
      a0[0] += f0.x; a0[1] += f0.y; a0[2] += f1.x; a0[3] += f1.y;
    }
    if (i1 < end) {
      uint2 w = Ts[(size_t)col[i1] * 4 + sub];
      const __half2* h = (const __half2*)&w;
      float2 f0 = __half22float2(h[0]), f1 = __half22float2(h[1]);
      a1[0] += f0.x; a1[1] += f0.y; a1[2] += f1.x; a1[3] += f1.y;
    }
  }
  float s[4];
#pragma unroll
  for (int j = 0; j < 4; j++) s[j] = a0[j] + a1[j];
#pragma unroll
  for (int j = 0; j < 4; j++) s[j] += __shfl_xor(s[j], 4);
#pragma unroll
  for (int j = 0; j < 4; j++) s[j] += __shfl_xor(s[j], 8);
#pragma unroll
  for (int j = 0; j < 4; j++) s[j] += __shfl_xor(s[j], 16);
#pragma unroll
  for (int j = 0; j < 4; j++) s[j] += __shfl_xor(s[j], 32);
  if (lane < 4) {
    float di = dinv[v];
    float4 b4 = ((const float4*)bias)[slice * 4 + sub];
    float4 r;
    r.x = di * s[0] + b4.x; r.y = di * s[1] + b4.y;
    r.z = di * s[2] + b4.z; r.w = di * s[3] + b4.w;
    r.x = r.x > 0.f ? r.x : 0.f;
    r.y = r.y > 0.f ? r.y : 0.f;
    r.z = r.z > 0.f ? r.z : 0.f;
    r.w = r.w > 0.f ? r.w : 0.f;
    *(float4*)(H + (size_t)v * HID + slice * 16 + sub * 4) = r;
  }
}

// ---------------------------------------------------------------------------
// Fused MLP head: out = relu(H @ Wp1 + bp1) @ Wp2 + bp2, thread-per-node
// ---------------------------------------------------------------------------
__global__ __launch_bounds__(256) void mlp_head(const float* __restrict__ H,
                                                const float* __restrict__ Wp1,
                                                const float* __restrict__ bp1,
                                                const float* __restrict__ Wp2,
                                                const float* __restrict__ bp2,
                                                float* __restrict__ out, int n) {
  __shared__ float W1t[32 * 64];
  __shared__ float w2s[32];
  __shared__ float b1s[32];
  for (int i = threadIdx.x; i < 64 * 32; i += 256) {
    int k = i >> 5, j = i & 31;
    W1t[j * 64 + k] = Wp1[i];
  }
  if (threadIdx.x < 32) {
    w2s[threadIdx.x] = Wp2[threadIdx.x];
    b1s[threadIdx.x] = bp1[threadIdx.x];
  }
  __syncthreads();
  int node = blockIdx.x * 256 + threadIdx.x;
  if (node >= n) return;
  float4 h[16];
  const float4* __restrict__ hr = (const float4*)(H + (size_t)node * 64);
#pragma unroll
  for (int j = 0; j < 16; j++) h[j] = hr[j];
  float o = bp2[0];
#pragma unroll
  for (int j = 0; j < 32; j++) {
    const float4* wr = (const float4*)(W1t + j * 64);
    float4 a4 = make_float4(0.f, 0.f, 0.f, 0.f);
#pragma unroll
    for (int k = 0; k < 16; k++) {
      float4 w = wr[k];
      a4.x += h[k].x * w.x;
      a4.y += h[k].y * w.y;
      a4.z += h[k].z * w.z;
      a4.w += h[k].w * w.w;
    }
    float a = a4.x + a4.y + a4.z + a4.w + b1s[j];
    a = a > 0.f ? a : 0.f;
    o += a * w2s[j];
  }
  out[node] = o;
}

// ---------------------------------------------------------------------------
extern "C" void kernel_launch(void* const* d_in, const int* in_sizes, int n_in,
                              void* d_out, int out_size, void* d_ws, size_t ws_size,
                              hipStream_t stream) {
  const float* x   = (const float*)d_in[0];
  const int* edge  = (const int*)d_in[1];
  const float* W1  = (const float*)d_in[3];
  const float* b1  = (const float*)d_in[4];
  const float* W2  = (const float*)d_in[5];
  const float* b2  = (const float*)d_in[6];
  const float* W3  = (const float*)d_in[7];
  const float* b3  = (const float*)d_in[8];
  const float* Wp1 = (const float*)d_in[9];
  const float* bp1 = (const float*)d_in[10];
  const float* Wp2 = (const float*)d_in[11];
  const float* bp2 = (const float*)d_in[12];
  float* out = (float*)d_out;

  const int n = in_sizes[0] / NDIM_IN;   // 100000
  const int E = in_sizes[1] / 2;         // 1600000
  const int* src = edge;
  const int* dst = edge + E;

  // workspace carve-out (256B aligned slices)
  char* ws = (char*)d_ws;
  size_t off = 0;
  auto carve = [&](size_t bytes) {
    char* p = ws + off;
    off = (off + bytes + 255) & ~(size_t)255;
    return p;
  };
  int*    histT = (int*)carve((size_t)NB * NC * 4);   // 800 KB
  int*    bsum  = (int*)carve(1024 * 4);
  int*    tmp   = (int*)carve((size_t)E * 4);         // 6.4 MB (packed)
  int*    col   = (int*)carve((size_t)E * 4);         // 6.4 MB
  int*    rp    = (int*)carve(((size_t)n + 1) * 4);
  float*  dinv  = (float*)carve((size_t)n * 4);
  __half* bufT  = (__half*)carve((size_t)n * HID * 2);   // 12.8 MB (sliced)
  float*  bufA  = (float*)carve((size_t)n * HID * 4);    // 25.6 MB
  (void)ws_size; (void)n_in; (void)out_size;

  const int nbN = (n + 255) / 256;        // 391
  const int ntiles = (n + 15) >> 4;       // 6250
  const int scan_len = NB * NC;           // 200192
  const int nbScan = (scan_len + 255) / 256;  // 782 == NB (alignment!)

  hist_k<<<NC, 256, 0, stream>>>(dst, histT, E);
  scan1<<<nbScan, 256, 0, stream>>>(histT, bsum, scan_len);
  scan2<<<1, 1024, 0, stream>>>(bsum, nbScan);
  scatter_k<<<NC, 256, 0, stream>>>(src, dst, histT, bsum, tmp, E);
  binsort_k<<<NB, 256, 0, stream>>>(tmp, bsum, col, rp, dinv, n, E);

  const int nbSp = ((n + 3) / 4) * 4;     // 100000 (4 nodes/block x 4 slices)

  // layer 1: 128 -> 64
  gemm_mfma<128><<<782, 256, 0, stream>>>(x, W1, dinv, bufT, n, ntiles);
  spmm_relu<<<nbSp, 256, 0, stream>>>(rp, col, bufT, dinv, b1, bufA, n);
  // layer 2: 64 -> 64
  gemm_mfma<64><<<782, 256, 0, stream>>>(bufA, W2, dinv, bufT, n, ntiles);
  spmm_relu<<<nbSp, 256, 0, stream>>>(rp, col, bufT, dinv, b2, bufA, n);
  // layer 3: 64 -> 64
  gemm_mfma<64><<<782, 256, 0, stream>>>(bufA, W3, dinv, bufT, n, ntiles);
  spmm_relu<<<nbSp, 256, 0, stream>>>(rp, col, bufT, dinv, b3, bufA, n);
  // head
  mlp_head<<<nbN, 256, 0, stream>>>(bufA, Wp1, bp1, Wp2, bp2, out, n);
}